// Round 6
// baseline (163.316 us; speedup 1.0000x reference)
//
#include <hip/hip_runtime.h>
#include <math.h>

// N=4, R=16384, K=96. Output: rgb [65536*3] | depth [65536] | weights [65536*95]
#define NRAYS     65536
#define RGB_OFF   0
#define DEPTH_OFF (NRAYS * 3)
#define W_OFF     (NRAYS * 4)

#define RPT  16              // rays per tile
#define TPB  8               // tiles per block
#define NBLK (NRAYS / (RPT * TPB))   // 512 blocks -> 2 blocks/CU, persistent

// per-buffer float offsets (pads absorb lane-15 overreads)
#define SHD_OFF   0          // 16*96 = 1536, pad to 1540
#define SHS_OFF   1540
#define SHR_OFF   3080       // 16*288 = 4608, pad to 4616
#define BUF_FLTS  7696       // 30784 B per buffer; x2 = 61568 B -> 2 blocks/CU

typedef float f4u __attribute__((ext_vector_type(4), aligned(4)));
typedef float f2u __attribute__((ext_vector_type(2), aligned(4)));

#define DPPF(oldv, x, ctrl)                                                    \
    __int_as_float(__builtin_amdgcn_update_dpp(                                \
        __float_as_int(oldv), __float_as_int(x), (ctrl), 0xF, 0xF, false))

// 1-alpha = exp(-delta*softplus(x)) via HW transcendentals. absmax 7.8e-3 ok.
__device__ __forceinline__ float one_minus_alpha(float x, float delta) {
    const float L2E = 1.44269504088896340736f;
    float xl = x * L2E;
    float l2 = (x > 20.0f) ? xl
                           : __builtin_amdgcn_logf(1.0f + __builtin_amdgcn_exp2f(xl));
    return __builtin_amdgcn_exp2f(-delta * l2);
}

__device__ __forceinline__ void gload_lds16(const float* g, float* l) {
    __builtin_amdgcn_global_load_lds(
        (const __attribute__((address_space(1))) void*)g,
        (__attribute__((address_space(3))) void*)l, 16, 0, 0);
}

// Issue one tile's 30 x 1KB DMA chunks, round-robin over the block's 4 waves.
// Waves 0,1 issue 8 chunks; waves 2,3 issue 7.
__device__ __forceinline__ void issue_tile(const float* __restrict__ rgbs,
                                           const float* __restrict__ sigmas,
                                           const float* __restrict__ depths,
                                           int tile, float* buf, int w, int l64) {
    const float* gd = depths + (size_t)tile * (RPT * 96);
    const float* gs = sigmas + (size_t)tile * (RPT * 96);
    const float* gr = rgbs   + (size_t)tile * (RPT * 288);
    for (int c = w; c < 30; c += 4) {
        const float* src; float* dst;
        if (c < 6)       { src = gd + c * 256;        dst = buf + SHD_OFF + c * 256; }
        else if (c < 12) { src = gs + (c - 6) * 256;  dst = buf + SHS_OFF + (c - 6) * 256; }
        else             { src = gr + (c - 12) * 256; dst = buf + SHR_OFF + (c - 12) * 256; }
        gload_lds16(src + l64 * 4, dst + l64 * 4);
    }
}

// ---------------------------------------------------------------------------
// R6: persistent double-buffered pipeline. Each block loops over 8 tiles:
// issue DMA(t+1) -> other buffer, wait own vmcnt(count(t+1)) so tile t's
// chunks are done while t+1's stay IN FLIGHT, raw s_barrier (no vmcnt(0)
// drain), compute tile t (16 lanes/ray, in-lane sequential transmittance,
// DPP row scan/reduce), barrier, swap. The request queue never drains --
// attacking the burst-then-drain pattern shared by R2/R4/R5.
// ---------------------------------------------------------------------------
__global__ __launch_bounds__(256) void integrate_kernel(
    const float* __restrict__ rgbs,     // [NRAYS, 96, 3]
    const float* __restrict__ sigmas,   // [NRAYS, 96]
    const float* __restrict__ depths,   // [NRAYS, 96]
    float* __restrict__ out)
{
    __shared__ float sh[2 * BUF_FLTS];

    const int t    = threadIdx.x;
    const int w    = t >> 6;
    const int l64  = t & 63;
    const int rb_  = t >> 4;            // ray within tile
    const int l    = t & 15;            // segment within ray
    const bool full = (l < 15);
    const int tile0 = blockIdx.x * TPB;

    issue_tile(rgbs, sigmas, depths, tile0, sh, w, l64);

    for (int i = 0; i < TPB; ++i) {
        float* buf = sh + (i & 1) * BUF_FLTS;

        if (i + 1 < TPB) {
            issue_tile(rgbs, sigmas, depths, tile0 + i + 1,
                       sh + ((i + 1) & 1) * BUF_FLTS, w, l64);
            // wait until only tile(i+1)'s own chunks remain outstanding
            if (w < 2) __builtin_amdgcn_s_waitcnt(0x0F78);   // vmcnt(8)
            else       __builtin_amdgcn_s_waitcnt(0x0F77);   // vmcnt(7)
        } else {
            __builtin_amdgcn_s_waitcnt(0x0F70);              // vmcnt(0)
        }
        __builtin_amdgcn_s_barrier();    // raw: no compiler vmcnt(0) drain

        const int ray = (tile0 + i) * RPT + rb_;
        const float* db = buf + SHD_OFF + rb_ * 96  + 6 * l;
        const float* sp = buf + SHS_OFF + rb_ * 96  + 6 * l;
        const float* rp = buf + SHR_OFF + rb_ * 288 + 18 * l;

        float2 e0 = *(const float2*)(db);
        float2 e1 = *(const float2*)(db + 2);
        float2 e2 = *(const float2*)(db + 4);
        float2 e3 = *(const float2*)(db + 6);
        float2 f0 = *(const float2*)(sp);
        float2 f1 = *(const float2*)(sp + 2);
        float2 f2v = *(const float2*)(sp + 4);
        float2 f3 = *(const float2*)(sp + 6);
        float2 c0 = *(const float2*)(rp);
        float2 c1 = *(const float2*)(rp + 2);
        float2 c2 = *(const float2*)(rp + 4);
        float2 c3 = *(const float2*)(rp + 6);
        float2 c4 = *(const float2*)(rp + 8);
        float2 c5 = *(const float2*)(rp + 10);
        float2 c6 = *(const float2*)(rp + 12);
        float2 c7 = *(const float2*)(rp + 14);
        float2 c8 = *(const float2*)(rp + 16);
        float2 c9 = *(const float2*)(rp + 18);
        float  r20 = rp[20];

        const float D[7] = {e0.x, e0.y, e1.x, e1.y, e2.x, e2.y, e3.x};
        const float S[7] = {f0.x, f0.y, f1.x, f1.y, f2v.x, f2v.y, f3.x};
        const float R[7] = {c0.x, c1.y, c3.x, c4.y, c6.x, c7.y, c9.x};
        const float G[7] = {c0.y, c2.x, c3.y, c5.x, c6.y, c8.x, c9.y};
        const float B[7] = {c1.x, c2.y, c4.x, c5.y, c7.x, c8.y, r20};

        float u[6];
        float Tloc = 1.0f;
        float Sw = 0.f, Sd = 0.f, Sr = 0.f, Sg = 0.f, Sbv = 0.f;

#define DO_IV(I)                                                      \
    { float delta = D[(I)+1] - D[I];                                  \
      float x = 0.5f * (S[I] + S[(I)+1]) - 1.0f;                      \
      float e = one_minus_alpha(x, delta);                            \
      float uu = (1.0f - e) * Tloc;                                   \
      Tloc *= e + 1e-10f;                                             \
      u[I] = uu;                                                      \
      Sw  += uu;                                                      \
      Sd  += uu * (0.5f * (D[I] + D[(I)+1]));                         \
      Sr  += uu * (0.5f * (R[I] + R[(I)+1]));                         \
      Sg  += uu * (0.5f * (G[I] + G[(I)+1]));                         \
      Sbv += uu * (0.5f * (B[I] + B[(I)+1])); }

        DO_IV(0) DO_IV(1) DO_IV(2) DO_IV(3) DO_IV(4)
        if (full) { DO_IV(5) } else { u[5] = 0.f; }
#undef DO_IV

        // exclusive prefix product of segment transmittances (DPP row scan)
        float incl = Tloc;
        incl *= DPPF(1.0f, incl, 0x111);
        incl *= DPPF(1.0f, incl, 0x112);
        incl *= DPPF(1.0f, incl, 0x114);
        incl *= DPPF(1.0f, incl, 0x118);
        float Tin = DPPF(1.0f, incl, 0x111);   // exclusive; lane0 = 1.0

        Sw *= Tin; Sd *= Tin; Sr *= Tin; Sg *= Tin; Sbv *= Tin;

#define RED(v)                         \
        v += DPPF(0.f, v, 0x111);      \
        v += DPPF(0.f, v, 0x112);      \
        v += DPPF(0.f, v, 0x114);      \
        v += DPPF(0.f, v, 0x118);
        RED(Sw) RED(Sd) RED(Sr) RED(Sg) RED(Sbv)
#undef RED

        float lo0 = 0.5f * (D[0] + D[1]);
        float lo  = DPPF(0.f, lo0, 0x11F);     // lane0 -> lane15

        float* wout = out + W_OFF + (size_t)ray * 95 + 6 * l;
        f4u v4 = { Tin * u[0], Tin * u[1], Tin * u[2], Tin * u[3] };
        *(f4u*)wout = v4;
        if (full) {
            f2u v2 = { Tin * u[4], Tin * u[5] };
            *(f2u*)(wout + 4) = v2;
        } else {
            wout[4] = Tin * u[4];
        }

        if (l == 15) {
            out[RGB_OFF + ray * 3 + 0] = 2.f * Sr  - 1.f;
            out[RGB_OFF + ray * 3 + 1] = 2.f * Sg  - 1.f;
            out[RGB_OFF + ray * 3 + 2] = 2.f * Sbv - 1.f;
            float dv = Sd / Sw;                    // normalize_depth
            float hi = 0.5f * (D[4] + D[5]);       // 0.5*(d[94]+d[95]) on lane 15
            dv = fmaxf(fminf(dv, hi), lo);         // NaN -> hi (ref: nan->inf->clip)
            out[DEPTH_OFF + ray] = dv;
        }

        __builtin_amdgcn_s_barrier();    // all reads of buf done before next DMA
    }
}

extern "C" void kernel_launch(void* const* d_in, const int* in_sizes, int n_in,
                              void* d_out, int out_size, void* d_ws, size_t ws_size,
                              hipStream_t stream) {
    const float* rgbs   = (const float*)d_in[0];
    const float* sigmas = (const float*)d_in[1];
    const float* depths = (const float*)d_in[2];
    float* out = (float*)d_out;

    // 512 persistent blocks x 8 tiles x 16 rays = 65536 rays
    integrate_kernel<<<NBLK, 256, 0, stream>>>(rgbs, sigmas, depths, out);
}

// Round 7
// 157.261 us; speedup vs baseline: 1.0385x; 1.0385x over previous
//
#include <hip/hip_runtime.h>
#include <math.h>

// N=4, R=16384, K=96. Output: rgb [65536*3] | depth [65536] | weights [65536*95]
#define NRAYS     65536
#define RGB_OFF   0
#define DEPTH_OFF (NRAYS * 3)
#define W_OFF     (NRAYS * 4)

#define RPB 16               // rays per block (256 threads, 4 waves, 16 lanes/ray)
// input staging layout (floats); pads absorb lane-15 overreads
#define SHD_OFF 0            // 16*96 = 1536 used, pad to 1540
#define SHS_OFF 1540
#define SHR_OFF 3080         // 16*288 = 4608 used, pad to 4616
#define SH_TOTAL 7696        // 30784 B
// output staging (reuses the input regions after compute)
#define WST_OFF 0            // 16*95 = 1520 floats (fits in SHD's 1540)
#define CST_OFF 1540         // 48 floats rgb
#define DST_OFF 1600         // 16 floats depth

typedef float f4u __attribute__((ext_vector_type(4), aligned(4)));

#define DPPF(oldv, x, ctrl)                                                    \
    __int_as_float(__builtin_amdgcn_update_dpp(                                \
        __float_as_int(oldv), __float_as_int(x), (ctrl), 0xF, 0xF, false))

// 1-alpha = exp(-delta*softplus(x)) via HW transcendentals. absmax 7.8e-3 ok.
__device__ __forceinline__ float one_minus_alpha(float x, float delta) {
    const float L2E = 1.44269504088896340736f;
    float xl = x * L2E;
    float l2 = (x > 20.0f) ? xl
                           : __builtin_amdgcn_logf(1.0f + __builtin_amdgcn_exp2f(xl));
    return __builtin_amdgcn_exp2f(-delta * l2);
}

__device__ __forceinline__ void gload_lds16(const float* g, float* l) {
    __builtin_amdgcn_global_load_lds(
        (const __attribute__((address_space(1))) void*)g,
        (__attribute__((address_space(3))) void*)l, 16, 0, 0);
}

// ---------------------------------------------------------------------------
// R7 = R5 (async DMA staging + 16-lanes/ray DPP compute) + FULL-LINE STORES:
// all outputs staged in LDS, then written as 16B-aligned dwordx4 covering
// exactly-aligned 64B lines (weights: 95 lines/block, rgb: 3, depth: 1).
// Eliminates the 4B-aligned line-straddling stores shared by R2..R6, testing
// the L2 write-allocate RMW theory for the ~3 TB/s plateau.
// ---------------------------------------------------------------------------
__global__ __launch_bounds__(256) void integrate_kernel(
    const float* __restrict__ rgbs,     // [NRAYS, 96, 3]
    const float* __restrict__ sigmas,   // [NRAYS, 96]
    const float* __restrict__ depths,   // [NRAYS, 96]
    float* __restrict__ out)
{
    __shared__ float sh[SH_TOTAL];

    const int t   = threadIdx.x;
    const int w   = t >> 6;
    const int l64 = t & 63;
    const int blk = blockIdx.x;

    // ---- async staging: 30 wave-chunks of 1024 B, round-robin over 4 waves ----
    {
        const float* gd = depths + (size_t)blk * (RPB * 96);
        const float* gs = sigmas + (size_t)blk * (RPB * 96);
        const float* gr = rgbs   + (size_t)blk * (RPB * 288);
        for (int c = w; c < 30; c += 4) {
            const float* src; float* dst;
            if (c < 6)       { src = gd + c * 256;        dst = sh + SHD_OFF + c * 256; }
            else if (c < 12) { src = gs + (c - 6) * 256;  dst = sh + SHS_OFF + (c - 6) * 256; }
            else             { src = gr + (c - 12) * 256; dst = sh + SHR_OFF + (c - 12) * 256; }
            gload_lds16(src + l64 * 4, dst + l64 * 4);
        }
    }
    __builtin_amdgcn_s_waitcnt(0x0F70);   // vmcnt(0)
    __syncthreads();

    // ---- fragment reads from LDS ----
    const int rb_ = t >> 4;             // ray within block
    const int l   = t & 15;             // segment within ray
    const bool full = (l < 15);

    const float* db = sh + SHD_OFF + rb_ * 96  + 6 * l;
    const float* sp = sh + SHS_OFF + rb_ * 96  + 6 * l;
    const float* rp = sh + SHR_OFF + rb_ * 288 + 18 * l;

    float2 e0 = *(const float2*)(db);
    float2 e1 = *(const float2*)(db + 2);
    float2 e2 = *(const float2*)(db + 4);
    float2 e3 = *(const float2*)(db + 6);
    float2 f0 = *(const float2*)(sp);
    float2 f1 = *(const float2*)(sp + 2);
    float2 f2v = *(const float2*)(sp + 4);
    float2 f3 = *(const float2*)(sp + 6);
    float2 c0 = *(const float2*)(rp);
    float2 c1 = *(const float2*)(rp + 2);
    float2 c2 = *(const float2*)(rp + 4);
    float2 c3 = *(const float2*)(rp + 6);
    float2 c4 = *(const float2*)(rp + 8);
    float2 c5 = *(const float2*)(rp + 10);
    float2 c6 = *(const float2*)(rp + 12);
    float2 c7 = *(const float2*)(rp + 14);
    float2 c8 = *(const float2*)(rp + 16);
    float2 c9 = *(const float2*)(rp + 18);
    float  r20 = rp[20];

    __syncthreads();   // all input reads done -> LDS reusable for output staging

    const float D[7] = {e0.x, e0.y, e1.x, e1.y, e2.x, e2.y, e3.x};
    const float S[7] = {f0.x, f0.y, f1.x, f1.y, f2v.x, f2v.y, f3.x};
    const float R[7] = {c0.x, c1.y, c3.x, c4.y, c6.x, c7.y, c9.x};
    const float G[7] = {c0.y, c2.x, c3.y, c5.x, c6.y, c8.x, c9.y};
    const float B[7] = {c1.x, c2.y, c4.x, c5.y, c7.x, c8.y, r20};

    // ---- in-lane sequential integration over 6 (5 on lane 15) intervals ----
    float u[6];
    float Tloc = 1.0f;
    float Sw = 0.f, Sd = 0.f, Sr = 0.f, Sg = 0.f, Sbv = 0.f;

#define DO_IV(I)                                                      \
    { float delta = D[(I)+1] - D[I];                                  \
      float x = 0.5f * (S[I] + S[(I)+1]) - 1.0f;                      \
      float e = one_minus_alpha(x, delta);                            \
      float uu = (1.0f - e) * Tloc;                                   \
      Tloc *= e + 1e-10f;                                             \
      u[I] = uu;                                                      \
      Sw  += uu;                                                      \
      Sd  += uu * (0.5f * (D[I] + D[(I)+1]));                         \
      Sr  += uu * (0.5f * (R[I] + R[(I)+1]));                         \
      Sg  += uu * (0.5f * (G[I] + G[(I)+1]));                         \
      Sbv += uu * (0.5f * (B[I] + B[(I)+1])); }

    DO_IV(0) DO_IV(1) DO_IV(2) DO_IV(3) DO_IV(4)
    if (full) { DO_IV(5) } else { u[5] = 0.f; }
#undef DO_IV

    // ---- exclusive prefix product of segment transmittances (DPP row scan) ----
    float incl = Tloc;
    incl *= DPPF(1.0f, incl, 0x111);
    incl *= DPPF(1.0f, incl, 0x112);
    incl *= DPPF(1.0f, incl, 0x114);
    incl *= DPPF(1.0f, incl, 0x118);
    float Tin = DPPF(1.0f, incl, 0x111);   // exclusive; lane0 = 1.0

    Sw *= Tin; Sd *= Tin; Sr *= Tin; Sg *= Tin; Sbv *= Tin;

#define RED(v)                         \
    v += DPPF(0.f, v, 0x111);          \
    v += DPPF(0.f, v, 0x112);          \
    v += DPPF(0.f, v, 0x114);          \
    v += DPPF(0.f, v, 0x118);
    RED(Sw) RED(Sd) RED(Sr) RED(Sg) RED(Sbv)
#undef RED

    float lo0 = 0.5f * (D[0] + D[1]);
    float lo  = DPPF(0.f, lo0, 0x11F);     // lane0 -> lane15

    // ---- stage outputs into LDS ----
    {
        float* wst = sh + WST_OFF + rb_ * 95 + 6 * l;   // 8B-aligned (6l even)
        float2* wst2 = (float2*)wst;
        wst2[0] = float2{Tin * u[0], Tin * u[1]};
        wst2[1] = float2{Tin * u[2], Tin * u[3]};
        if (full) wst2[2] = float2{Tin * u[4], Tin * u[5]};
        else      wst[4]  = Tin * u[4];
    }
    if (l == 15) {
        sh[CST_OFF + rb_ * 3 + 0] = 2.f * Sr  - 1.f;
        sh[CST_OFF + rb_ * 3 + 1] = 2.f * Sg  - 1.f;
        sh[CST_OFF + rb_ * 3 + 2] = 2.f * Sbv - 1.f;
        float dv = Sd / Sw;                    // normalize_depth
        float hi = 0.5f * (D[4] + D[5]);       // 0.5*(d[94]+d[95]) on lane 15
        dv = fmaxf(fminf(dv, hi), lo);         // NaN -> hi (ref: nan->inf->clip)
        sh[DST_OFF + rb_] = dv;
    }
    __syncthreads();

    // ---- cooperative full-line stores (all 16B-aligned, spans 64B-aligned) ----
    // weights: 1520 floats = 95 full 64B lines, base byte = 1MB + blk*6080 (64-al.)
    {
        float* wbase = out + W_OFF + (size_t)blk * (RPB * 95);
        const float4* src = (const float4*)(sh + WST_OFF);
        float4* dst = (float4*)wbase;
        dst[t] = src[t];                       // 256 f4 = 4096 B
        if (t < 124) dst[256 + t] = src[256 + t];   // remaining 1984 B
    }
    // rgb: 48 floats = 3 lines, base byte = blk*192 (64-aligned)
    if (t < 12) {
        ((float4*)(out + RGB_OFF + (size_t)blk * (RPB * 3)))[t] =
            ((const float4*)(sh + CST_OFF))[t];
    }
    // depth: 16 floats = 1 line, base byte = 786432 + blk*64 (64-aligned)
    if (t < 4) {
        ((float4*)(out + DEPTH_OFF + (size_t)blk * RPB))[t] =
            ((const float4*)(sh + DST_OFF))[t];
    }
}

extern "C" void kernel_launch(void* const* d_in, const int* in_sizes, int n_in,
                              void* d_out, int out_size, void* d_ws, size_t ws_size,
                              hipStream_t stream) {
    const float* rgbs   = (const float*)d_in[0];
    const float* sigmas = (const float*)d_in[1];
    const float* depths = (const float*)d_in[2];
    float* out = (float*)d_out;

    // 16 rays per 256-thread block -> 4096 blocks
    integrate_kernel<<<NRAYS / RPB, 256, 0, stream>>>(rgbs, sigmas, depths, out);
}

// Round 9
// 149.462 us; speedup vs baseline: 1.0927x; 1.0522x over previous
//
#include <hip/hip_runtime.h>
#include <math.h>

// N=4, R=16384, K=96. Output: rgb [65536*3] | depth [65536] | weights [65536*95]
#define NRAYS     65536
#define RGB_OFF   0
#define DEPTH_OFF (NRAYS * 3)
#define W_OFF     (NRAYS * 4)

#define RPB 16               // rays per block (256 threads, 4 waves, 16 lanes/ray)
// input staging layout (floats); pads absorb lane-15 overreads
#define SHD_OFF 0            // 16*96 = 1536 used, pad to 1540
#define SHS_OFF 1540
#define SHR_OFF 3080         // 16*288 = 4608 used, pad to 4616
#define SH_TOTAL 7696        // 30784 B -> 5 blocks/CU
// output staging (reuses the input regions after compute)
#define WST_OFF 0            // 16*95 = 1520 floats
#define CST_OFF 1540         // 48 floats rgb
#define DST_OFF 1600         // 16 floats depth

// ext_vector float4: required by __builtin_nontemporal_store (HIP's float4
// is a class type the builtin rejects).
typedef float v4f __attribute__((ext_vector_type(4)));

#define DPPF(oldv, x, ctrl)                                                    \
    __int_as_float(__builtin_amdgcn_update_dpp(                                \
        __float_as_int(oldv), __float_as_int(x), (ctrl), 0xF, 0xF, false))

// 1-alpha = exp(-delta*softplus(x)) via HW transcendentals. absmax 7.8e-3 ok.
__device__ __forceinline__ float one_minus_alpha(float x, float delta) {
    const float L2E = 1.44269504088896340736f;
    float xl = x * L2E;
    float l2 = (x > 20.0f) ? xl
                           : __builtin_amdgcn_logf(1.0f + __builtin_amdgcn_exp2f(xl));
    return __builtin_amdgcn_exp2f(-delta * l2);
}

// async global->LDS DMA, 16 B/lane, aux=2 -> NT (streaming) cache policy:
// inputs are read exactly once, so don't allocate/pollute L2 with them.
__device__ __forceinline__ void gload_lds16(const float* g, float* l) {
    __builtin_amdgcn_global_load_lds(
        (const __attribute__((address_space(1))) void*)g,
        (__attribute__((address_space(3))) void*)l, 16, 0, 2);
}

// ---------------------------------------------------------------------------
// R8 = R7 + memory-path hints only (clean ceiling probe):
//  (1) NT on the input DMA (no L2 allocate for use-once inputs),
//  (2) nontemporal output stores,
//  (3) XCD-contiguous block swizzle: dispatch round-robins blockIdx across 8
//      XCDs, so logical blk = (id&7)*512 + id>>3 gives each XCD one
//      contiguous 1/8 of the input range in its private L2.
// Compute identical to R7 (16 lanes/ray, in-lane sequential transmittance,
// DPP row scan/reduce, LDS-staged full-line stores).
// ---------------------------------------------------------------------------
__global__ __launch_bounds__(256) void integrate_kernel(
    const float* __restrict__ rgbs,     // [NRAYS, 96, 3]
    const float* __restrict__ sigmas,   // [NRAYS, 96]
    const float* __restrict__ depths,   // [NRAYS, 96]
    float* __restrict__ out)
{
    __shared__ float sh[SH_TOTAL];

    const int t   = threadIdx.x;
    const int w   = t >> 6;
    const int l64 = t & 63;
    // XCD-contiguous swizzle: 4096 blocks = 8 XCDs x 512 contiguous
    const int blk = ((blockIdx.x & 7) << 9) | (blockIdx.x >> 3);

    // ---- async NT staging: 30 wave-chunks of 1024 B over 4 waves ----
    {
        const float* gd = depths + (size_t)blk * (RPB * 96);
        const float* gs = sigmas + (size_t)blk * (RPB * 96);
        const float* gr = rgbs   + (size_t)blk * (RPB * 288);
        for (int c = w; c < 30; c += 4) {
            const float* src; float* dst;
            if (c < 6)       { src = gd + c * 256;        dst = sh + SHD_OFF + c * 256; }
            else if (c < 12) { src = gs + (c - 6) * 256;  dst = sh + SHS_OFF + (c - 6) * 256; }
            else             { src = gr + (c - 12) * 256; dst = sh + SHR_OFF + (c - 12) * 256; }
            gload_lds16(src + l64 * 4, dst + l64 * 4);
        }
    }
    __builtin_amdgcn_s_waitcnt(0x0F70);   // vmcnt(0)
    __syncthreads();

    // ---- fragment reads from LDS ----
    const int rb_ = t >> 4;             // ray within block
    const int l   = t & 15;             // segment within ray
    const bool full = (l < 15);

    const float* db = sh + SHD_OFF + rb_ * 96  + 6 * l;
    const float* sp = sh + SHS_OFF + rb_ * 96  + 6 * l;
    const float* rp = sh + SHR_OFF + rb_ * 288 + 18 * l;

    float2 e0 = *(const float2*)(db);
    float2 e1 = *(const float2*)(db + 2);
    float2 e2 = *(const float2*)(db + 4);
    float2 e3 = *(const float2*)(db + 6);
    float2 f0 = *(const float2*)(sp);
    float2 f1 = *(const float2*)(sp + 2);
    float2 f2v = *(const float2*)(sp + 4);
    float2 f3 = *(const float2*)(sp + 6);
    float2 c0 = *(const float2*)(rp);
    float2 c1 = *(const float2*)(rp + 2);
    float2 c2 = *(const float2*)(rp + 4);
    float2 c3 = *(const float2*)(rp + 6);
    float2 c4 = *(const float2*)(rp + 8);
    float2 c5 = *(const float2*)(rp + 10);
    float2 c6 = *(const float2*)(rp + 12);
    float2 c7 = *(const float2*)(rp + 14);
    float2 c8 = *(const float2*)(rp + 16);
    float2 c9 = *(const float2*)(rp + 18);
    float  r20 = rp[20];

    __syncthreads();   // input reads done -> LDS reusable for output staging

    const float D[7] = {e0.x, e0.y, e1.x, e1.y, e2.x, e2.y, e3.x};
    const float S[7] = {f0.x, f0.y, f1.x, f1.y, f2v.x, f2v.y, f3.x};
    const float R[7] = {c0.x, c1.y, c3.x, c4.y, c6.x, c7.y, c9.x};
    const float G[7] = {c0.y, c2.x, c3.y, c5.x, c6.y, c8.x, c9.y};
    const float B[7] = {c1.x, c2.y, c4.x, c5.y, c7.x, c8.y, r20};

    // ---- in-lane sequential integration over 6 (5 on lane 15) intervals ----
    float u[6];
    float Tloc = 1.0f;
    float Sw = 0.f, Sd = 0.f, Sr = 0.f, Sg = 0.f, Sbv = 0.f;

#define DO_IV(I)                                                      \
    { float delta = D[(I)+1] - D[I];                                  \
      float x = 0.5f * (S[I] + S[(I)+1]) - 1.0f;                      \
      float e = one_minus_alpha(x, delta);                            \
      float uu = (1.0f - e) * Tloc;                                   \
      Tloc *= e + 1e-10f;                                             \
      u[I] = uu;                                                      \
      Sw  += uu;                                                      \
      Sd  += uu * (0.5f * (D[I] + D[(I)+1]));                         \
      Sr  += uu * (0.5f * (R[I] + R[(I)+1]));                         \
      Sg  += uu * (0.5f * (G[I] + G[(I)+1]));                         \
      Sbv += uu * (0.5f * (B[I] + B[(I)+1])); }

    DO_IV(0) DO_IV(1) DO_IV(2) DO_IV(3) DO_IV(4)
    if (full) { DO_IV(5) } else { u[5] = 0.f; }
#undef DO_IV

    // ---- exclusive prefix product of segment transmittances (DPP row scan) ----
    float incl = Tloc;
    incl *= DPPF(1.0f, incl, 0x111);
    incl *= DPPF(1.0f, incl, 0x112);
    incl *= DPPF(1.0f, incl, 0x114);
    incl *= DPPF(1.0f, incl, 0x118);
    float Tin = DPPF(1.0f, incl, 0x111);   // exclusive; lane0 = 1.0

    Sw *= Tin; Sd *= Tin; Sr *= Tin; Sg *= Tin; Sbv *= Tin;

#define RED(v)                         \
    v += DPPF(0.f, v, 0x111);          \
    v += DPPF(0.f, v, 0x112);          \
    v += DPPF(0.f, v, 0x114);          \
    v += DPPF(0.f, v, 0x118);
    RED(Sw) RED(Sd) RED(Sr) RED(Sg) RED(Sbv)
#undef RED

    float lo0 = 0.5f * (D[0] + D[1]);
    float lo  = DPPF(0.f, lo0, 0x11F);     // lane0 -> lane15

    // ---- stage outputs into LDS ----
    {
        float* wst = sh + WST_OFF + rb_ * 95 + 6 * l;   // 8B-aligned
        float2* wst2 = (float2*)wst;
        wst2[0] = float2{Tin * u[0], Tin * u[1]};
        wst2[1] = float2{Tin * u[2], Tin * u[3]};
        if (full) wst2[2] = float2{Tin * u[4], Tin * u[5]};
        else      wst[4]  = Tin * u[4];
    }
    if (l == 15) {
        sh[CST_OFF + rb_ * 3 + 0] = 2.f * Sr  - 1.f;
        sh[CST_OFF + rb_ * 3 + 1] = 2.f * Sg  - 1.f;
        sh[CST_OFF + rb_ * 3 + 2] = 2.f * Sbv - 1.f;
        float dv = Sd / Sw;                    // normalize_depth
        float hi = 0.5f * (D[4] + D[5]);       // 0.5*(d[94]+d[95]) on lane 15
        dv = fmaxf(fminf(dv, hi), lo);         // NaN -> hi (ref: nan->inf->clip)
        sh[DST_OFF + rb_] = dv;
    }
    __syncthreads();

    // ---- cooperative full-line nontemporal stores (64B-aligned spans) ----
    {
        v4f* dst = (v4f*)(out + W_OFF + (size_t)blk * (RPB * 95));
        const v4f* src = (const v4f*)(sh + WST_OFF);
        __builtin_nontemporal_store(src[t], dst + t);                 // 4096 B
        if (t < 124) __builtin_nontemporal_store(src[256 + t], dst + 256 + t);
    }
    if (t < 12) {
        __builtin_nontemporal_store(
            ((const v4f*)(sh + CST_OFF))[t],
            (v4f*)(out + RGB_OFF + (size_t)blk * (RPB * 3)) + t);
    }
    if (t < 4) {
        __builtin_nontemporal_store(
            ((const v4f*)(sh + DST_OFF))[t],
            (v4f*)(out + DEPTH_OFF + (size_t)blk * RPB) + t);
    }
}

extern "C" void kernel_launch(void* const* d_in, const int* in_sizes, int n_in,
                              void* d_out, int out_size, void* d_ws, size_t ws_size,
                              hipStream_t stream) {
    const float* rgbs   = (const float*)d_in[0];
    const float* sigmas = (const float*)d_in[1];
    const float* depths = (const float*)d_in[2];
    float* out = (float*)d_out;

    // 16 rays per 256-thread block -> 4096 blocks
    integrate_kernel<<<NRAYS / RPB, 256, 0, stream>>>(rgbs, sigmas, depths, out);
}